// Round 9
// baseline (2285.011 us; speedup 1.0000x reference)
//
#include <hip/hip_runtime.h>
#include <math.h>

#define NSWEEP 6
#define NR (NSWEEP * 63)

// ---------------------------------------------------------------------------
// Kernel 1: partial max-pooled outer products. Grid = B*G blocks.
// ---------------------------------------------------------------------------
__global__ __launch_bounds__(256) void pool_kernel(const float* __restrict__ x,
                                                   float* __restrict__ part,
                                                   int G) {
  __shared__ float xs[4096];
  const int t = threadIdx.x;
  const int blk = blockIdx.x;
  const int b = blk / G, g = blk % G;
  const int npb = 4096 / G;
  const int ntile = npb >> 6;
  const int n0 = g * npb;
  const int i0 = (t >> 4) * 4;
  const int j0 = (t & 15) * 4;

  float mv[4][4];
#pragma unroll
  for (int a = 0; a < 4; ++a)
#pragma unroll
    for (int c = 0; c < 4; ++c) mv[a][c] = -INFINITY;

  const float4* src = reinterpret_cast<const float4*>(x + ((size_t)b * 4096 + n0) * 64);
  float4* xs4 = reinterpret_cast<float4*>(xs);

  for (int tile = 0; tile < ntile; ++tile) {
#pragma unroll
    for (int q = 0; q < 4; ++q) xs4[t + 256 * q] = src[(size_t)tile * 1024 + t + 256 * q];
    __syncthreads();
#pragma unroll 4
    for (int n = 0; n < 64; ++n) {
      const float4 vi = *reinterpret_cast<const float4*>(&xs[n * 64 + i0]);
      const float4 vj = *reinterpret_cast<const float4*>(&xs[n * 64 + j0]);
      const float fi[4] = {vi.x, vi.y, vi.z, vi.w};
      const float fj[4] = {vj.x, vj.y, vj.z, vj.w};
#pragma unroll
      for (int a = 0; a < 4; ++a)
#pragma unroll
        for (int c = 0; c < 4; ++c)
          mv[a][c] = fmaxf(mv[a][c], fi[a] * fj[c]);
    }
    __syncthreads();
  }

#pragma unroll
  for (int a = 0; a < 4; ++a)
#pragma unroll
    for (int c = 0; c < 4; ++c)
      xs[(i0 + a) * 64 + (j0 + c)] = mv[a][c];
  __syncthreads();

  float* dst = part + ((size_t)b * G + g) * 4096;
#pragma unroll
  for (int q = 0; q < 16; ++q) dst[t + 256 * q] = xs[t + 256 * q];
}

// ---------------------------------------------------------------------------
// Kernel 2: grid 4 x 512 threads. Block owns 4 batches.
//   waves 0-3: Jacobi producers (one batch each, full column in regs)
//   waves 4-7: V-replay consumers (LDS ring per batch, R6-proven sync)
// 2 waves/SIMD guaranteed -> TLP fills each chain's lgkmcnt stalls.
// W, V go to global; kernel 3 reconstructs.
// ---------------------------------------------------------------------------
__device__ __forceinline__ float bperm(int byteaddr, float v) {
  return __int_as_float(__builtin_amdgcn_ds_bpermute(byteaddr, __float_as_int(v)));
}

__device__ __forceinline__ int partner_of(int lane, int r) {
  if (lane == 0) { int q = 62 + r; if (q >= 63) q -= 63; return 1 + q; }
  int u = lane - 1 - r; if (u < 0) u += 63;
  if (u == 62) return 0;
  int m = 61 - u + r; if (m >= 63) m -= 63; return 1 + m;
}

#define DOT64(dst, g, ex)                                                     \
  {                                                                           \
    float d0_ = 0, d1_ = 0, d2_ = 0, d3_ = 0;                                 \
    _Pragma("unroll") for (int k_ = 0; k_ < 64; k_ += 4) {                    \
      d0_ = fmaf(g[k_], ex[k_], d0_);                                         \
      d1_ = fmaf(g[k_ + 1], ex[k_ + 1], d1_);                                 \
      d2_ = fmaf(g[k_ + 2], ex[k_ + 2], d2_);                                 \
      d3_ = fmaf(g[k_ + 3], ex[k_ + 3], d3_);                                 \
    }                                                                         \
    dst = (d0_ + d1_) + (d2_ + d3_);                                          \
  }

#define NORM64(dst, g)                                                        \
  {                                                                           \
    float n0_ = 0, n1_ = 0, n2_ = 0, n3_ = 0;                                 \
    _Pragma("unroll") for (int k_ = 0; k_ < 64; k_ += 4) {                    \
      n0_ = fmaf(g[k_], g[k_], n0_);                                          \
      n1_ = fmaf(g[k_ + 1], g[k_ + 1], n1_);                                  \
      n2_ = fmaf(g[k_ + 2], g[k_ + 2], n2_);                                  \
      n3_ = fmaf(g[k_ + 3], g[k_ + 3], n3_);                                  \
    }                                                                         \
    dst = (n0_ + n1_) + (n2_ + n3_);                                          \
  }

__global__ __launch_bounds__(512, 1) void svd_kernel(const float* __restrict__ part,
                                                     float* __restrict__ Wg,
                                                     float* __restrict__ Vg, int G) {
  __shared__ float2 ring[4][64][64];   // 4 batches x 64 slots x 64 lanes = 128KB
  __shared__ int pflags[4], cflags[4];

  const int t = threadIdx.x;
  const int wave = t >> 6, lane = t & 63;
  const int slot = wave & 3;
  const int batch = blockIdx.x * 4 + slot;

  if (t < 4) { pflags[t] = 0; cflags[t] = 0; }
  __syncthreads();

  int* pf = &pflags[slot];
  int* cf = &cflags[slot];

  if (wave < 4) {
    // ======================= producer =======================
    float g[64], ex[64];
    const float* pb = part + (size_t)batch * G * 4096;
#pragma unroll 4
    for (int k = 0; k < 64; ++k) {
      float m = pb[k * 64 + lane];                       // coalesced per k
      for (int gg = 1; gg < G; ++gg)
        m = fmaxf(m, pb[(size_t)gg * 4096 + k * 64 + lane]);
      g[k] = m;
    }

    float a;
    NORM64(a, g);

    int rr = 0;
    int partner = partner_of(lane, 0);
    int addr = partner << 2;
#pragma unroll
    for (int k = 0; k < 64; ++k) ex[k] = bperm(addr, g[k]);
    float bb = bperm(addr, a);

#pragma unroll 1
    for (int rg = 0; rg < NR; ++rg) {
      float d;
      DOT64(d, g, ex);

      // two-rsqrt angle: c identical on both pair lanes, s opposite sign
      const float u = (bb - a) * 0.5f;                   // exactly negated on partner
      const float sg = (u != 0.0f) ? copysignf(1.0f, u)
                                   : ((lane < partner) ? 1.0f : -1.0f);
      const float q = fmaf(u, u, d * d);
      float c, s;
      if (q > 0.0f) {
        const float rh = rsqrtf(q);                      // 1/h
        const float cc = fmaf(0.5f * fabsf(u), rh, 0.5f);  // c^2 = (1+|u|/h)/2
        const float rc = rsqrtf(cc);                     // 1/c
        c = cc * rc;                                     // c = sqrt(c^2)
        s = d * sg * rh * 0.5f * rc;                     // s = d*sg/(2hc)
      } else {
        c = 1.0f; s = 0.0f;
      }

      ring[slot][rg & 63][lane] = make_float2(c, s);     // plain ds_write
      if ((rg & 15) == 15) {
        if (lane == 0)
          __hip_atomic_store(pf, rg + 1, __ATOMIC_RELEASE, __HIP_MEMORY_SCOPE_WORKGROUP);
        int cd = __hip_atomic_load(cf, __ATOMIC_ACQUIRE, __HIP_MEMORY_SCOPE_WORKGROUP);
        while (rg + 1 - cd > 40) {
          __builtin_amdgcn_s_sleep(2);
          cd = __hip_atomic_load(cf, __ATOMIC_ACQUIRE, __HIP_MEMORY_SCOPE_WORKGROUP);
        }
      }

      const float ns = -s;
      rr = (rr == 62) ? 0 : rr + 1;
      partner = partner_of(lane, rr);
      addr = partner << 2;

      // fused: rotate own column, immediately issue next round's exchange
#pragma unroll
      for (int k = 0; k < 64; ++k) {
        g[k] = fmaf(ns, ex[k], c * g[k]);
        ex[k] = bperm(addr, g[k]);
      }

      if (rr == 0) { NORM64(a, g); }                     // sweep boundary refresh
      else a = fmaf(c * c, a, fmaf(s * s, bb, -2.0f * (c * s) * d));
      bb = bperm(addr, a);
    }
    if (lane == 0)
      __hip_atomic_store(pf, NR, __ATOMIC_RELEASE, __HIP_MEMORY_SCOPE_WORKGROUP);

    // W = G * diag(sigma^{-1/2}) -> global, row-major, coalesced per k
    float s2;
    NORM64(s2, g);
    const float sigma = sqrtf(s2);
    const float coef = (sigma > 1e-30f) ? rsqrtf(sigma) : 0.0f;
    float* wdst = Wg + (size_t)batch * 4096;
#pragma unroll
    for (int k = 0; k < 64; ++k) wdst[k * 64 + lane] = g[k] * coef;

  } else {
    // ======================= consumer =======================
    float v[64], ex[64];
#pragma unroll
    for (int k = 0; k < 64; ++k) v[k] = (k == lane) ? 1.0f : 0.0f;

    int rr = 0;
    int partner = partner_of(lane, 0);
    int addr = partner << 2;
#pragma unroll
    for (int k = 0; k < 64; ++k) ex[k] = bperm(addr, v[k]);

    int seen = 0;
#pragma unroll 1
    for (int rg = 0; rg < NR; ++rg) {
      if (seen < rg + 1) {
        for (;;) {
          seen = __hip_atomic_load(pf, __ATOMIC_ACQUIRE, __HIP_MEMORY_SCOPE_WORKGROUP);
          if (seen >= rg + 1) break;
          __builtin_amdgcn_s_sleep(2);
        }
      }
      const float2 cs = ring[slot][rg & 63][lane];
      const float c = cs.x, ns = -cs.y;

      rr = (rr == 62) ? 0 : rr + 1;
      partner = partner_of(lane, rr);
      addr = partner << 2;

#pragma unroll
      for (int k = 0; k < 64; ++k) {
        v[k] = fmaf(ns, ex[k], c * v[k]);
        ex[k] = bperm(addr, v[k]);
      }
      if ((rg & 15) == 15 && lane == 0)
        __hip_atomic_store(cf, rg + 1, __ATOMIC_RELEASE, __HIP_MEMORY_SCOPE_WORKGROUP);
    }
    float* vdst = Vg + (size_t)batch * 4096;
#pragma unroll
    for (int k = 0; k < 64; ++k) vdst[k * 64 + lane] = v[k];   // row-major V
  }
}

// ---------------------------------------------------------------------------
// Kernel 3: R = W * V^T, L2-normalize, store. Grid 16 x 256 (R3-proven).
// ---------------------------------------------------------------------------
__global__ __launch_bounds__(256) void recon_kernel(const float* __restrict__ Wg,
                                                    const float* __restrict__ Vg,
                                                    float* __restrict__ out) {
  __shared__ __align__(16) float Vl[64 * 68];
  __shared__ __align__(16) float Rl[64 * 68];
  __shared__ float red[4];

  const int b = blockIdx.x;
  const int t = threadIdx.x;
  const int wave = t >> 6, lane = t & 63;

  // stage V (row-major) into LDS stride 68
#pragma unroll
  for (int u = 0; u < 16; ++u) {
    const int e = t + 256 * u;
    Vl[(e >> 6) * 68 + (e & 63)] = Vg[(size_t)b * 4096 + e];
  }
  __syncthreads();

  // my row of W from global (per-lane contiguous 256B, L2-resident)
  float wr[64];
  const float4* wrow = reinterpret_cast<const float4*>(Wg + (size_t)b * 4096 + lane * 64);
#pragma unroll
  for (int jb = 0; jb < 16; ++jb) {
    const float4 v4 = wrow[jb];
    wr[4 * jb] = v4.x; wr[4 * jb + 1] = v4.y; wr[4 * jb + 2] = v4.z; wr[4 * jb + 3] = v4.w;
  }

  const int j0 = wave * 16;
  float rvals[16];
  float ssq = 0.0f;
#pragma unroll 4
  for (int jj = 0; jj < 16; ++jj) {
    const float4* vr = reinterpret_cast<const float4*>(&Vl[(j0 + jj) * 68]);
    float c0 = 0, c1 = 0, c2 = 0, c3 = 0;
#pragma unroll
    for (int kb = 0; kb < 16; ++kb) {
      const float4 vv = vr[kb];   // broadcast: conflict-free
      c0 = fmaf(wr[4 * kb], vv.x, c0);
      c1 = fmaf(wr[4 * kb + 1], vv.y, c1);
      c2 = fmaf(wr[4 * kb + 2], vv.z, c2);
      c3 = fmaf(wr[4 * kb + 3], vv.w, c3);
    }
    const float accv = (c0 + c1) + (c2 + c3);  // R[lane][j0+jj]
    rvals[jj] = accv;
    ssq = fmaf(accv, accv, ssq);
  }
#pragma unroll
  for (int jj = 0; jj < 4; ++jj)
    *reinterpret_cast<float4*>(&Rl[lane * 68 + j0 + 4 * jj]) =
        make_float4(rvals[4 * jj], rvals[4 * jj + 1], rvals[4 * jj + 2], rvals[4 * jj + 3]);

#pragma unroll
  for (int off = 32; off; off >>= 1) ssq += __shfl_xor(ssq, off, 64);
  if (lane == 0) red[wave] = ssq;
  __syncthreads();
  const float rn = rsqrtf(fmaxf(red[0] + red[1] + red[2] + red[3], 1e-24f));

#pragma unroll
  for (int u = 0; u < 16; ++u) {
    const int e = t + 256 * u;
    out[(size_t)b * 4096 + e] = Rl[(e >> 6) * 68 + (e & 63)] * rn;
  }
}

extern "C" void kernel_launch(void* const* d_in, const int* in_sizes, int n_in,
                              void* d_out, int out_size, void* d_ws, size_t ws_size,
                              hipStream_t stream) {
  const float* x = (const float*)d_in[0];
  float* out = (float*)d_out;

  // ws layout (floats): [Wg 16*4096][Vg 16*4096][part 16*G*4096]
  float* wsf = (float*)d_ws;
  float* Wg = wsf;
  float* Vg = wsf + (size_t)16 * 4096;
  float* part = Vg + (size_t)16 * 4096;
  const size_t base = (size_t)2 * 16 * 4096 * 4;

  int G = 16;
  while (G > 1 && base + (size_t)16 * G * 4096 * 4 > ws_size) G >>= 1;

  pool_kernel<<<dim3(16 * G), dim3(256), 0, stream>>>(x, part, G);
  svd_kernel<<<dim3(4), dim3(512), 0, stream>>>(part, Wg, Vg, G);
  recon_kernel<<<dim3(16), dim3(256), 0, stream>>>(Wg, Vg, out);
}

// Round 10
// 382.309 us; speedup vs baseline: 5.9769x; 5.9769x over previous
//
#include <hip/hip_runtime.h>
#include <math.h>

#define NSWEEP 6
#define NR (NSWEEP * 63)

// ---------------------------------------------------------------------------
// Kernel 1: partial max-pooled outer products. Grid = B*G blocks.
// ---------------------------------------------------------------------------
__global__ __launch_bounds__(256) void pool_kernel(const float* __restrict__ x,
                                                   float* __restrict__ part,
                                                   int G) {
  __shared__ float xs[4096];
  const int t = threadIdx.x;
  const int blk = blockIdx.x;
  const int b = blk / G, g = blk % G;
  const int npb = 4096 / G;
  const int ntile = npb >> 6;
  const int n0 = g * npb;
  const int i0 = (t >> 4) * 4;
  const int j0 = (t & 15) * 4;

  float mv[4][4];
#pragma unroll
  for (int a = 0; a < 4; ++a)
#pragma unroll
    for (int c = 0; c < 4; ++c) mv[a][c] = -INFINITY;

  const float4* src = reinterpret_cast<const float4*>(x + ((size_t)b * 4096 + n0) * 64);
  float4* xs4 = reinterpret_cast<float4*>(xs);

  for (int tile = 0; tile < ntile; ++tile) {
#pragma unroll
    for (int q = 0; q < 4; ++q) xs4[t + 256 * q] = src[(size_t)tile * 1024 + t + 256 * q];
    __syncthreads();
#pragma unroll 4
    for (int n = 0; n < 64; ++n) {
      const float4 vi = *reinterpret_cast<const float4*>(&xs[n * 64 + i0]);
      const float4 vj = *reinterpret_cast<const float4*>(&xs[n * 64 + j0]);
      const float fi[4] = {vi.x, vi.y, vi.z, vi.w};
      const float fj[4] = {vj.x, vj.y, vj.z, vj.w};
#pragma unroll
      for (int a = 0; a < 4; ++a)
#pragma unroll
        for (int c = 0; c < 4; ++c)
          mv[a][c] = fmaxf(mv[a][c], fi[a] * fj[c]);
    }
    __syncthreads();
  }

#pragma unroll
  for (int a = 0; a < 4; ++a)
#pragma unroll
    for (int c = 0; c < 4; ++c)
      xs[(i0 + a) * 64 + (j0 + c)] = mv[a][c];
  __syncthreads();

  float* dst = part + ((size_t)b * G + g) * 4096;
#pragma unroll
  for (int q = 0; q < 16; ++q) dst[t + 256 * q] = xs[t + 256 * q];
}

// ---------------------------------------------------------------------------
// Kernel 2: one-sided Jacobi, XOR tournament (pairs lane^m, m=1..63).
//   wave0 producer: g[64] in regs, NO ex[] buffer (in-place re-fetch via
//     ds_bpermute, rotate fused with next round's dot fetch) -> ~80 VGPRs.
//   wave1 consumer: V replay from LDS ring (R6-proven sync).
//   waves 2,3 park; all 4 waves run the R = W*V^T epilogue.
// ---------------------------------------------------------------------------
__device__ __forceinline__ float bperm(int byteaddr, float v) {
  return __int_as_float(__builtin_amdgcn_ds_bpermute(byteaddr, __float_as_int(v)));
}

#define NORM64(dst, g)                                                        \
  {                                                                           \
    float n0_ = 0, n1_ = 0, n2_ = 0, n3_ = 0;                                 \
    _Pragma("unroll") for (int k_ = 0; k_ < 64; k_ += 4) {                    \
      n0_ = fmaf(g[k_], g[k_], n0_);                                          \
      n1_ = fmaf(g[k_ + 1], g[k_ + 1], n1_);                                  \
      n2_ = fmaf(g[k_ + 2], g[k_ + 2], n2_);                                  \
      n3_ = fmaf(g[k_ + 3], g[k_ + 3], n3_);                                  \
    }                                                                         \
    dst = (n0_ + n1_) + (n2_ + n3_);                                          \
  }

__global__ __launch_bounds__(256, 1) void svd_kernel(const float* __restrict__ part,
                                                     float* __restrict__ out, int G) {
  __shared__ __align__(16) float Al[64 * 68];   // pooled A -> W -> R
  __shared__ __align__(16) float Vl[64 * 68];   // final V
  __shared__ float2 ring[64][64];
  __shared__ float red[4];
  __shared__ int pflag_s, cflag_s;

  const int b = blockIdx.x;
  const int t = threadIdx.x;
  const int wave = t >> 6, lane = t & 63;
  const int lane4 = lane << 2;

  if (t == 0) { pflag_s = 0; cflag_s = 0; }

  // ---- prologue: fused max-reduce of partials into Al (all 256 threads) ----
  const float4* p4 = reinterpret_cast<const float4*>(part) + (size_t)b * G * 1024;
  float4 acc[4];
#pragma unroll
  for (int u = 0; u < 4; ++u) acc[u] = p4[t + 256 * u];
#pragma unroll 2
  for (int g = 1; g < G; ++g) {
#pragma unroll
    for (int u = 0; u < 4; ++u) {
      const float4 v = p4[(size_t)g * 1024 + t + 256 * u];
      acc[u].x = fmaxf(acc[u].x, v.x);
      acc[u].y = fmaxf(acc[u].y, v.y);
      acc[u].z = fmaxf(acc[u].z, v.z);
      acc[u].w = fmaxf(acc[u].w, v.w);
    }
  }
#pragma unroll
  for (int u = 0; u < 4; ++u) {
    const int idx = t + 256 * u;
    const int i = idx >> 4;
    const int j = (idx & 15) * 4;
    *reinterpret_cast<float4*>(&Al[i * 68 + j]) = acc[u];
  }
  __syncthreads();

  if (wave == 0) {
    // ================= producer: G columns, no ex[] buffer =================
    float g[64];
#pragma unroll
    for (int k = 0; k < 64; ++k) g[k] = Al[k * 68 + lane];

    float a;
    NORM64(a, g);

    int m = 1;
    int addr = lane4 ^ (m << 2);

    // initial dot for round 0 (m=1)
    float d;
    {
      float d0 = 0, d1 = 0, d2 = 0, d3 = 0;
#pragma unroll
      for (int k = 0; k < 64; k += 4) {
        d0 = fmaf(g[k], bperm(addr, g[k]), d0);
        d1 = fmaf(g[k + 1], bperm(addr, g[k + 1]), d1);
        d2 = fmaf(g[k + 2], bperm(addr, g[k + 2]), d2);
        d3 = fmaf(g[k + 3], bperm(addr, g[k + 3]), d3);
      }
      d = (d0 + d1) + (d2 + d3);
    }
    float bb = bperm(addr, a);

#pragma unroll 1
    for (int rg = 0; rg < NR; ++rg) {
      const int partner = lane ^ m;
      // angle: c identical on both pair lanes, s opposite sign
      const float u = (bb - a) * 0.5f;                  // exactly negated on partner
      const float sg = (u != 0.0f) ? copysignf(1.0f, u)
                                   : ((lane < partner) ? 1.0f : -1.0f);
      const float q = fmaf(u, u, d * d);
      float c, s;
      if (q > 0.0f) {
        const float rh = rsqrtf(q);                     // 1/h
        const float cc = fmaf(0.5f * fabsf(u), rh, 0.5f);  // c^2
        const float rc = rsqrtf(cc);
        c = cc * rc;
        s = d * sg * rh * 0.5f * rc;
      } else {
        c = 1.0f; s = 0.0f;
      }

      ring[rg & 63][lane] = make_float2(c, s);
      if ((rg & 15) == 15) {
        if (lane == 0)
          __hip_atomic_store(&pflag_s, rg + 1, __ATOMIC_RELEASE, __HIP_MEMORY_SCOPE_WORKGROUP);
        int cd = __hip_atomic_load(&cflag_s, __ATOMIC_ACQUIRE, __HIP_MEMORY_SCOPE_WORKGROUP);
        while (rg + 1 - cd > 40) {
          __builtin_amdgcn_s_sleep(2);
          cd = __hip_atomic_load(&cflag_s, __ATOMIC_ACQUIRE, __HIP_MEMORY_SCOPE_WORKGROUP);
        }
      }

      const int mn = (m == 63) ? 1 : m + 1;
      const int addrn = lane4 ^ (mn << 2);
      const float ns = -s;

      // fused: re-fetch old partner, rotate in place, fetch next partner, dot
      float d0 = 0, d1 = 0, d2 = 0, d3 = 0;
#pragma unroll
      for (int k = 0; k < 64; k += 4) {
        const float e0 = bperm(addr, g[k]);
        const float e1 = bperm(addr, g[k + 1]);
        const float e2 = bperm(addr, g[k + 2]);
        const float e3 = bperm(addr, g[k + 3]);
        g[k] = fmaf(ns, e0, c * g[k]);
        g[k + 1] = fmaf(ns, e1, c * g[k + 1]);
        g[k + 2] = fmaf(ns, e2, c * g[k + 2]);
        g[k + 3] = fmaf(ns, e3, c * g[k + 3]);
        d0 = fmaf(g[k], bperm(addrn, g[k]), d0);
        d1 = fmaf(g[k + 1], bperm(addrn, g[k + 1]), d1);
        d2 = fmaf(g[k + 2], bperm(addrn, g[k + 2]), d2);
        d3 = fmaf(g[k + 3], bperm(addrn, g[k + 3]), d3);
      }

      if (mn == 1) { NORM64(a, g); }                    // sweep boundary refresh
      else a = fmaf(c * c, a, fmaf(s * s, bb, -2.0f * (c * s) * d));
      bb = bperm(addrn, a);
      d = (d0 + d1) + (d2 + d3);
      m = mn; addr = addrn;
    }
    if (lane == 0)
      __hip_atomic_store(&pflag_s, NR, __ATOMIC_RELEASE, __HIP_MEMORY_SCOPE_WORKGROUP);

    // exact sigma; W = G * diag(sigma^{-1/2}) into Al
    float s2;
    NORM64(s2, g);
    const float sigma = sqrtf(s2);
    const float coef = (sigma > 1e-30f) ? rsqrtf(sigma) : 0.0f;
#pragma unroll
    for (int k = 0; k < 64; ++k) Al[k * 68 + lane] = g[k] * coef;

  } else if (wave == 1) {
    // ================= consumer: V columns (replay) =================
    float v[64];
#pragma unroll
    for (int k = 0; k < 64; ++k) v[k] = (k == lane) ? 1.0f : 0.0f;

    int m = 1;
    int addr = lane4 ^ (m << 2);
    int seen = 0;
#pragma unroll 1
    for (int rg = 0; rg < NR; ++rg) {
      if (seen < rg + 1) {
        for (;;) {
          seen = __hip_atomic_load(&pflag_s, __ATOMIC_ACQUIRE, __HIP_MEMORY_SCOPE_WORKGROUP);
          if (seen >= rg + 1) break;
          __builtin_amdgcn_s_sleep(2);
        }
      }
      const float2 cs = ring[rg & 63][lane];
      const float c = cs.x, ns = -cs.y;

#pragma unroll
      for (int k = 0; k < 64; k += 4) {
        const float e0 = bperm(addr, v[k]);
        const float e1 = bperm(addr, v[k + 1]);
        const float e2 = bperm(addr, v[k + 2]);
        const float e3 = bperm(addr, v[k + 3]);
        v[k] = fmaf(ns, e0, c * v[k]);
        v[k + 1] = fmaf(ns, e1, c * v[k + 1]);
        v[k + 2] = fmaf(ns, e2, c * v[k + 2]);
        v[k + 3] = fmaf(ns, e3, c * v[k + 3]);
      }
      m = (m == 63) ? 1 : m + 1;
      addr = lane4 ^ (m << 2);

      if ((rg & 15) == 15 && lane == 0)
        __hip_atomic_store(&cflag_s, rg + 1, __ATOMIC_RELEASE, __HIP_MEMORY_SCOPE_WORKGROUP);
    }
#pragma unroll
    for (int k = 0; k < 64; ++k) Vl[k * 68 + lane] = v[k];
  }
  // waves 2,3 park here
  __syncthreads();

  // ---- R = W * V^T; each wave computes 16 columns for all 64 rows ----
  float wr[64];
#pragma unroll
  for (int jb = 0; jb < 16; ++jb) {
    const float4 v4 = *reinterpret_cast<const float4*>(&Al[lane * 68 + jb * 4]);
    wr[4 * jb] = v4.x; wr[4 * jb + 1] = v4.y; wr[4 * jb + 2] = v4.z; wr[4 * jb + 3] = v4.w;
  }
  __syncthreads();  // snapshots taken; Al rows free for R

  const int j0 = wave * 16;
  float rvals[16];
  float ssq = 0.0f;
#pragma unroll 4
  for (int jj = 0; jj < 16; ++jj) {
    const float4* vr = reinterpret_cast<const float4*>(&Vl[(j0 + jj) * 68]);
    float c0 = 0, c1 = 0, c2 = 0, c3 = 0;
#pragma unroll
    for (int kb = 0; kb < 16; ++kb) {
      const float4 vv = vr[kb];   // broadcast: conflict-free
      c0 = fmaf(wr[4 * kb], vv.x, c0);
      c1 = fmaf(wr[4 * kb + 1], vv.y, c1);
      c2 = fmaf(wr[4 * kb + 2], vv.z, c2);
      c3 = fmaf(wr[4 * kb + 3], vv.w, c3);
    }
    const float accv = (c0 + c1) + (c2 + c3);  // R[lane][j0+jj]
    rvals[jj] = accv;
    ssq = fmaf(accv, accv, ssq);
  }
#pragma unroll
  for (int jj = 0; jj < 4; ++jj)
    *reinterpret_cast<float4*>(&Al[lane * 68 + j0 + 4 * jj]) =
        make_float4(rvals[4 * jj], rvals[4 * jj + 1], rvals[4 * jj + 2], rvals[4 * jj + 3]);

  // ---- ||R||_F^2 reduction, normalize, coalesced store ----
#pragma unroll
  for (int off = 32; off; off >>= 1) ssq += __shfl_xor(ssq, off, 64);
  if (lane == 0) red[wave] = ssq;
  __syncthreads();
  const float rn = rsqrtf(fmaxf(red[0] + red[1] + red[2] + red[3], 1e-24f));

#pragma unroll
  for (int u = 0; u < 16; ++u) {
    const int e = t + 256 * u;
    out[(size_t)b * 4096 + e] = Al[(e >> 6) * 68 + (e & 63)] * rn;
  }
}

extern "C" void kernel_launch(void* const* d_in, const int* in_sizes, int n_in,
                              void* d_out, int out_size, void* d_ws, size_t ws_size,
                              hipStream_t stream) {
  const float* x = (const float*)d_in[0];
  float* out = (float*)d_out;
  float* part = (float*)d_ws;

  int G = 32;
  while (G > 1 && (size_t)16 * G * 4096 * 4 > ws_size) G >>= 1;

  pool_kernel<<<dim3(16 * G), dim3(256), 0, stream>>>(x, part, G);
  svd_kernel<<<dim3(16), dim3(256), 0, stream>>>(part, out, G);
}

// Round 11
// 309.997 us; speedup vs baseline: 7.3711x; 1.2333x over previous
//
#include <hip/hip_runtime.h>
#include <math.h>

#define NSWEEP 6
#define NR (NSWEEP * 63)
#define SKIP_EPS 5e-6f

// ---------------------------------------------------------------------------
// Kernel 1: partial max-pooled outer products. Grid = B*G blocks.
// ---------------------------------------------------------------------------
__global__ __launch_bounds__(256) void pool_kernel(const float* __restrict__ x,
                                                   float* __restrict__ part,
                                                   int G) {
  __shared__ float xs[4096];
  const int t = threadIdx.x;
  const int blk = blockIdx.x;
  const int b = blk / G, g = blk % G;
  const int npb = 4096 / G;
  const int ntile = npb >> 6;
  const int n0 = g * npb;
  const int i0 = (t >> 4) * 4;
  const int j0 = (t & 15) * 4;

  float mv[4][4];
#pragma unroll
  for (int a = 0; a < 4; ++a)
#pragma unroll
    for (int c = 0; c < 4; ++c) mv[a][c] = -INFINITY;

  const float4* src = reinterpret_cast<const float4*>(x + ((size_t)b * 4096 + n0) * 64);
  float4* xs4 = reinterpret_cast<float4*>(xs);

  for (int tile = 0; tile < ntile; ++tile) {
#pragma unroll
    for (int q = 0; q < 4; ++q) xs4[t + 256 * q] = src[(size_t)tile * 1024 + t + 256 * q];
    __syncthreads();
#pragma unroll 4
    for (int n = 0; n < 64; ++n) {
      const float4 vi = *reinterpret_cast<const float4*>(&xs[n * 64 + i0]);
      const float4 vj = *reinterpret_cast<const float4*>(&xs[n * 64 + j0]);
      const float fi[4] = {vi.x, vi.y, vi.z, vi.w};
      const float fj[4] = {vj.x, vj.y, vj.z, vj.w};
#pragma unroll
      for (int a = 0; a < 4; ++a)
#pragma unroll
        for (int c = 0; c < 4; ++c)
          mv[a][c] = fmaxf(mv[a][c], fi[a] * fj[c]);
    }
    __syncthreads();
  }

#pragma unroll
  for (int a = 0; a < 4; ++a)
#pragma unroll
    for (int c = 0; c < 4; ++c)
      xs[(i0 + a) * 64 + (j0 + c)] = mv[a][c];
  __syncthreads();

  float* dst = part + ((size_t)b * G + g) * 4096;
#pragma unroll
  for (int q = 0; q < 16; ++q) dst[t + 256 * q] = xs[t + 256 * q];
}

// ---------------------------------------------------------------------------
// Kernel 2: one-sided Jacobi, XOR schedule (pairs lane^m, m=1..63).
//   wave0 producer: g[64]+ex[64] cached (R6-proven fused rotate+next-fetch),
//     XOR addressing (0 bank conflicts), threshold-skip vote in late sweeps.
//   wave1 consumer: V replay from LDS ring (R6-proven sync), skip-aware.
//   waves 2,3 park; all 4 waves run the R = W*V^T epilogue.
// ---------------------------------------------------------------------------
__device__ __forceinline__ float bperm(int byteaddr, float v) {
  return __int_as_float(__builtin_amdgcn_ds_bpermute(byteaddr, __float_as_int(v)));
}

#define NORM64(dst, g)                                                        \
  {                                                                           \
    float n0_ = 0, n1_ = 0, n2_ = 0, n3_ = 0;                                 \
    _Pragma("unroll") for (int k_ = 0; k_ < 64; k_ += 4) {                    \
      n0_ = fmaf(g[k_], g[k_], n0_);                                          \
      n1_ = fmaf(g[k_ + 1], g[k_ + 1], n1_);                                  \
      n2_ = fmaf(g[k_ + 2], g[k_ + 2], n2_);                                  \
      n3_ = fmaf(g[k_ + 3], g[k_ + 3], n3_);                                  \
    }                                                                         \
    dst = (n0_ + n1_) + (n2_ + n3_);                                          \
  }

__global__ __launch_bounds__(256, 1) void svd_kernel(const float* __restrict__ part,
                                                     float* __restrict__ out, int G) {
  __shared__ __align__(16) float Al[64 * 68];   // pooled A -> W -> R
  __shared__ __align__(16) float Vl[64 * 68];   // final V
  __shared__ float2 ring[64][64];
  __shared__ float red[4];
  __shared__ int pflag_s, cflag_s;

  const int b = blockIdx.x;
  const int t = threadIdx.x;
  const int wave = t >> 6, lane = t & 63;
  const int lane4 = lane << 2;

  if (t == 0) { pflag_s = 0; cflag_s = 0; }

  // ---- prologue: fused max-reduce of partials into Al (all 256 threads) ----
  const float4* p4 = reinterpret_cast<const float4*>(part) + (size_t)b * G * 1024;
  float4 acc[4];
#pragma unroll
  for (int u = 0; u < 4; ++u) acc[u] = p4[t + 256 * u];
#pragma unroll 2
  for (int g = 1; g < G; ++g) {
#pragma unroll
    for (int u = 0; u < 4; ++u) {
      const float4 v = p4[(size_t)g * 1024 + t + 256 * u];
      acc[u].x = fmaxf(acc[u].x, v.x);
      acc[u].y = fmaxf(acc[u].y, v.y);
      acc[u].z = fmaxf(acc[u].z, v.z);
      acc[u].w = fmaxf(acc[u].w, v.w);
    }
  }
#pragma unroll
  for (int u = 0; u < 4; ++u) {
    const int idx = t + 256 * u;
    const int i = idx >> 4;
    const int j = (idx & 15) * 4;
    *reinterpret_cast<float4*>(&Al[i * 68 + j]) = acc[u];
  }
  __syncthreads();

  if (wave == 0) {
    // ================= producer: G columns, ex[] cached =================
    float g[64], ex[64];
#pragma unroll
    for (int k = 0; k < 64; ++k) g[k] = Al[k * 68 + lane];

    float a;
    NORM64(a, g);

    int m = 1;
    int addr = lane4 ^ (m << 2);
#pragma unroll
    for (int k = 0; k < 64; ++k) ex[k] = bperm(addr, g[k]);
    float bb = bperm(addr, a);

#pragma unroll 1
    for (int rg = 0; rg < NR; ++rg) {
      // dot product over cached partner column
      float d0 = 0, d1 = 0, d2 = 0, d3 = 0;
#pragma unroll
      for (int k = 0; k < 64; k += 4) {
        d0 = fmaf(g[k], ex[k], d0);
        d1 = fmaf(g[k + 1], ex[k + 1], d1);
        d2 = fmaf(g[k + 2], ex[k + 2], d2);
        d3 = fmaf(g[k + 3], ex[k + 3], d3);
      }
      const float d = (d0 + d1) + (d2 + d3);

      // angle: c identical on both pair lanes, s opposite sign
      const int partner = lane ^ m;
      const float u = (bb - a) * 0.5f;                  // exactly negated on partner
      const float sg = (u != 0.0f) ? copysignf(1.0f, u)
                                   : ((lane < partner) ? 1.0f : -1.0f);
      const float q = fmaf(u, u, d * d);
      float c, s;
      if (q > 0.0f) {
        const float rh = rsqrtf(q);                     // 1/h
        const float cc = fmaf(0.5f * fabsf(u), rh, 0.5f);  // c^2
        const float rc = rsqrtf(cc);
        c = cc * rc;
        s = d * sg * rh * 0.5f * rc;
      } else {
        c = 1.0f; s = 0.0f;
      }

      // wave-uniform tiny-rotation skip (late sweeps)
      const bool skip = __all(fabsf(s) < SKIP_EPS);

      ring[rg & 63][lane] = skip ? make_float2(1.0f, 0.0f) : make_float2(c, s);
      if ((rg & 15) == 15) {
        if (lane == 0)
          __hip_atomic_store(&pflag_s, rg + 1, __ATOMIC_RELEASE, __HIP_MEMORY_SCOPE_WORKGROUP);
        int cd = __hip_atomic_load(&cflag_s, __ATOMIC_ACQUIRE, __HIP_MEMORY_SCOPE_WORKGROUP);
        while (rg + 1 - cd > 40) {
          __builtin_amdgcn_s_sleep(2);
          cd = __hip_atomic_load(&cflag_s, __ATOMIC_ACQUIRE, __HIP_MEMORY_SCOPE_WORKGROUP);
        }
      }

      const int mn = (m == 63) ? 1 : m + 1;
      const int addrn = lane4 ^ (mn << 2);

      if (!skip) {
        const float ns = -s;
        // fused: rotate own column, immediately issue next round's exchange
#pragma unroll
        for (int k = 0; k < 64; ++k) {
          g[k] = fmaf(ns, ex[k], c * g[k]);
          ex[k] = bperm(addrn, g[k]);
        }
        if (mn == 1) { NORM64(a, g); }                  // sweep boundary refresh
        else a = fmaf(c * c, a, fmaf(s * s, bb, -2.0f * (c * s) * d));
      } else {
        // no rotation: fetch next partner from unchanged g; a unchanged
#pragma unroll
        for (int k = 0; k < 64; ++k) ex[k] = bperm(addrn, g[k]);
      }
      bb = bperm(addrn, a);
      m = mn; addr = addrn;
    }
    if (lane == 0)
      __hip_atomic_store(&pflag_s, NR, __ATOMIC_RELEASE, __HIP_MEMORY_SCOPE_WORKGROUP);

    // exact sigma; W = G * diag(sigma^{-1/2}) into Al
    float s2;
    NORM64(s2, g);
    const float sigma = sqrtf(s2);
    const float coef = (sigma > 1e-30f) ? rsqrtf(sigma) : 0.0f;
#pragma unroll
    for (int k = 0; k < 64; ++k) Al[k * 68 + lane] = g[k] * coef;

  } else if (wave == 1) {
    // ================= consumer: V columns (replay, skip-aware) =================
    float v[64];
#pragma unroll
    for (int k = 0; k < 64; ++k) v[k] = (k == lane) ? 1.0f : 0.0f;

    int m = 1;
    int addr = lane4 ^ (m << 2);
    int seen = 0;
#pragma unroll 1
    for (int rg = 0; rg < NR; ++rg) {
      if (seen < rg + 1) {
        for (;;) {
          seen = __hip_atomic_load(&pflag_s, __ATOMIC_ACQUIRE, __HIP_MEMORY_SCOPE_WORKGROUP);
          if (seen >= rg + 1) break;
          __builtin_amdgcn_s_sleep(2);
        }
      }
      const float2 cs = ring[rg & 63][lane];
      const bool skip = __all(cs.y == 0.0f);

      if (!skip) {
        const float c = cs.x, ns = -cs.y;
#pragma unroll
        for (int k = 0; k < 64; k += 4) {
          const float e0 = bperm(addr, v[k]);
          const float e1 = bperm(addr, v[k + 1]);
          const float e2 = bperm(addr, v[k + 2]);
          const float e3 = bperm(addr, v[k + 3]);
          v[k] = fmaf(ns, e0, c * v[k]);
          v[k + 1] = fmaf(ns, e1, c * v[k + 1]);
          v[k + 2] = fmaf(ns, e2, c * v[k + 2]);
          v[k + 3] = fmaf(ns, e3, c * v[k + 3]);
        }
      }
      m = (m == 63) ? 1 : m + 1;
      addr = lane4 ^ (m << 2);

      if ((rg & 15) == 15 && lane == 0)
        __hip_atomic_store(&cflag_s, rg + 1, __ATOMIC_RELEASE, __HIP_MEMORY_SCOPE_WORKGROUP);
    }
#pragma unroll
    for (int k = 0; k < 64; ++k) Vl[k * 68 + lane] = v[k];
  }
  // waves 2,3 park here
  __syncthreads();

  // ---- R = W * V^T; each wave computes 16 columns for all 64 rows ----
  float wr[64];
#pragma unroll
  for (int jb = 0; jb < 16; ++jb) {
    const float4 v4 = *reinterpret_cast<const float4*>(&Al[lane * 68 + jb * 4]);
    wr[4 * jb] = v4.x; wr[4 * jb + 1] = v4.y; wr[4 * jb + 2] = v4.z; wr[4 * jb + 3] = v4.w;
  }
  __syncthreads();  // snapshots taken; Al rows free for R

  const int j0 = wave * 16;
  float rvals[16];
  float ssq = 0.0f;
#pragma unroll 4
  for (int jj = 0; jj < 16; ++jj) {
    const float4* vr = reinterpret_cast<const float4*>(&Vl[(j0 + jj) * 68]);
    float c0 = 0, c1 = 0, c2 = 0, c3 = 0;
#pragma unroll
    for (int kb = 0; kb < 16; ++kb) {
      const float4 vv = vr[kb];   // broadcast: conflict-free
      c0 = fmaf(wr[4 * kb], vv.x, c0);
      c1 = fmaf(wr[4 * kb + 1], vv.y, c1);
      c2 = fmaf(wr[4 * kb + 2], vv.z, c2);
      c3 = fmaf(wr[4 * kb + 3], vv.w, c3);
    }
    const float accv = (c0 + c1) + (c2 + c3);  // R[lane][j0+jj]
    rvals[jj] = accv;
    ssq = fmaf(accv, accv, ssq);
  }
#pragma unroll
  for (int jj = 0; jj < 4; ++jj)
    *reinterpret_cast<float4*>(&Al[lane * 68 + j0 + 4 * jj]) =
        make_float4(rvals[4 * jj], rvals[4 * jj + 1], rvals[4 * jj + 2], rvals[4 * jj + 3]);

  // ---- ||R||_F^2 reduction, normalize, coalesced store ----
#pragma unroll
  for (int off = 32; off; off >>= 1) ssq += __shfl_xor(ssq, off, 64);
  if (lane == 0) red[wave] = ssq;
  __syncthreads();
  const float rn = rsqrtf(fmaxf(red[0] + red[1] + red[2] + red[3], 1e-24f));

#pragma unroll
  for (int u = 0; u < 16; ++u) {
    const int e = t + 256 * u;
    out[(size_t)b * 4096 + e] = Al[(e >> 6) * 68 + (e & 63)] * rn;
  }
}

extern "C" void kernel_launch(void* const* d_in, const int* in_sizes, int n_in,
                              void* d_out, int out_size, void* d_ws, size_t ws_size,
                              hipStream_t stream) {
  const float* x = (const float*)d_in[0];
  float* out = (float*)d_out;
  float* part = (float*)d_ws;

  int G = 32;
  while (G > 1 && (size_t)16 * G * 4096 * 4 > ws_size) G >>= 1;

  pool_kernel<<<dim3(16 * G), dim3(256), 0, stream>>>(x, part, G);
  svd_kernel<<<dim3(16), dim3(256), 0, stream>>>(part, out, G);
}